// Round 10
// baseline (83.630 us; speedup 1.0000x reference)
//
#include <hip/hip_runtime.h>
#include <cmath>

#define DD     10
#define FF     32
#define OUTN   32
#define PPW    6                 // pairs per tile (60 rows, lanes 60-63 shadow)
#define NTILE  2                 // tiles per wave, software-pipelined
#define NW     2                 // waves per block
#define NT     (NW * 64)
#define RPT    (PPW * DD)        // 60 rows per tile
#define HR     (RPT / 2)         // 30 iterations per half-lane per tile
#define STRIDE 36                // LDS row stride in floats (144 B, 16B-aligned)

typedef float f32x4 __attribute__((ext_vector_type(4)));
typedef float f32x2 __attribute__((ext_vector_type(2)));

// Kernel 1: summed[b,v,f] = sum_d inputs[b,v,d,f]  — at its roofline
__global__ __launch_bounds__(256) void sum_d4_kernel(
    const f32x4* __restrict__ in, f32x4* __restrict__ out, int n4) {
    int idx = blockIdx.x * 256 + threadIdx.x;
    if (idx >= n4) return;
    int f4 = idx & 7;
    int bv = idx >> 3;
    const f32x4* p = in + (size_t)bv * (DD * 8) + f4;
    f32x4 s = __builtin_nontemporal_load(p);
#pragma unroll
    for (int d = 1; d < DD; ++d) s += __builtin_nontemporal_load(p + d * 8);
    out[idx] = s;
}

// slot-lane prep: packed gather descriptor (byte-offset | maskbit) + zm
__device__ __forceinline__ int make_gidx(
    const int* __restrict__ adj, const float* __restrict__ mask,
    int tr0, int lane, int NR, int V, int mask_index, float& zm_s) {
    int sr = tr0 + lane;
    if (sr >= NR) sr = NR - 1;
    int a = adj[sr];
    zm_s = 1.f - mask[sr];
    int ac = a < 0 ? 0 : (a >= V ? V - 1 : a);              // JAX clamp
    int bv_s = sr / DD;
    int b_s = (bv_s >= 2 * V) ? ((bv_s >= 3 * V) ? 3 : 2) : ((bv_s >= V) ? 1 : 0);
    return ((b_s * V + ac) << 7) | ((a == mask_index) ? 1 : 0);
}

// stage 2 for one tile: per-lane-row dense + softmax + writeback + epilogue
__device__ __forceinline__ void process_tile(
    float* tbase, int tr0, float zm_s, int lane, int slot, bool own, int pe,
    const f32x2* __restrict__ W2, const f32x2* __restrict__ b2,
    const f32x2* __restrict__ A2, float* __restrict__ out, int NR) {
    float* rowp = tbase + slot * STRIDE;
    f32x4 gi4[8];
#pragma unroll
    for (int q = 0; q < 8; ++q) gi4[q] = *(const f32x4*)(rowp + 4 * q);

    const float zm_o = __int_as_float(
        __builtin_amdgcn_ds_bpermute(slot << 2, __float_as_int(zm_s)));

    f32x2 T2[16];
#pragma unroll
    for (int i = 0; i < 16; ++i) T2[i] = (f32x2){0.f, 0.f};
#pragma unroll
    for (int ff = 0; ff < FF; ++ff) {
        float gf = gi4[ff >> 2][ff & 3];
        f32x2 gf2 = {gf, gf};
#pragma unroll
        for (int i = 0; i < 16; ++i) T2[i] = gf2 * W2[ff * 16 + i] + T2[i];
    }
    f32x2 z2 = {zm_o, zm_o};
    f32x2 acc2 = {0.f, 0.f};
#pragma unroll
    for (int i = 0; i < 16; ++i) {
        f32x2 v = z2 * T2[i] + b2[i];
        v.x = fmaxf(v.x, 0.f);
        v.y = fmaxf(v.y, 0.f);
        v = v * z2;
        T2[i] = v;
        acc2 = v * A2[i] + acc2;
    }
    const float aw = acc2.x + acc2.y - 1e7f * (1.f - zm_o);

    const int pe40 = pe * 40;
    float vals[DD];
    float mx = -INFINITY;
#pragma unroll
    for (int d = 0; d < DD; ++d) {
        vals[d] = __int_as_float(
            __builtin_amdgcn_ds_bpermute(pe40 + 4 * d, __float_as_int(aw)));
        mx = fmaxf(mx, vals[d]);
    }
    float den = 0.f;
#pragma unroll
    for (int d = 0; d < DD; ++d) den += __expf(vals[d] - mx);
    const float coef = __expf(aw - mx) / den;

    if (own) {
        f32x2 c2 = {coef, coef};
#pragma unroll
        for (int q = 0; q < 8; ++q) {
            f32x2 lo = T2[2 * q] * c2;
            f32x2 hv = T2[2 * q + 1] * c2;
            f32x4 vv;
            vv.x = lo.x; vv.y = lo.y; vv.z = hv.x; vv.w = hv.y;
            *(f32x4*)(rowp + 4 * q) = vv;
        }
    }

    int nrows = NR - tr0;
    if (nrows < 0) nrows = 0;
    if (nrows > RPT) nrows = RPT;
    const int lim4 = nrows * 8;
    f32x4* ob = (f32x4*)(out + (size_t)tr0 * FF);
#pragma unroll
    for (int k = 0; k < 8; ++k) {
        int m = lane + (k << 6);
        if (m < lim4) {
            const f32x4 v = *(const f32x4*)(tbase + (m >> 3) * STRIDE + ((m & 7) << 2));
            __builtin_nontemporal_store(v, ob + m);
        }
    }
}

// Kernel 2: two tiles per wave, pipelined: t1 loads in flight under t0 compute.
__global__ __launch_bounds__(NT) void gat_kernel(
    const float* __restrict__ summed,
    const float* __restrict__ init,
    const float* __restrict__ mask,
    const float* __restrict__ Wk,
    const float* __restrict__ Wb,
    const float* __restrict__ Ak,
    const int* __restrict__ adj,
    const int* __restrict__ mask_index_p,
    float* __restrict__ out,
    int B, int V) {
    __shared__ float sROW[NW][NTILE][RPT][STRIDE];   // 34560 B

    const int t    = threadIdx.x;
    const int lane = t & 63;
    const int w    = t >> 6;
    const int f    = lane & 31;
    const int hi   = lane >> 5;
    const int vhi4 = hi << 2;
    const int BV   = B * V;
    const int NR   = BV * DD;
    const int mask_index = *mask_index_p;
    const char* sum_bytes = (const char*)summed;

    const int wp0 = (blockIdx.x * NW + w) * (NTILE * PPW);
    const int tr0 = wp0 * DD;
    const int tr1 = tr0 + RPT;
    const bool full0 = (wp0 + PPW) <= BV;
    const bool full1 = (wp0 + 2 * PPW) <= BV;

    // ---- P1: tile0 prep + descriptors ----
    float zm0;
    const int gidx0 = make_gidx(adj, mask, tr0, lane, NR, V, mask_index, zm0);
    int gp0[HR];
#pragma unroll
    for (int i = 0; i < HR; ++i)
        gp0[i] = __builtin_amdgcn_ds_bpermute((i << 3) + vhi4, gidx0);

    // ---- P2: tile0 loads (gather + init), all in flight ----
    float g0[HR], iv0[HR];
#pragma unroll
    for (int i = 0; i < HR; ++i)
        g0[i] = *(const float*)(sum_bytes + (uint32_t)((gp0[i] & ~127) | (f << 2)));
    if (full0) {
        const float* ip = init + (size_t)tr0 * FF + lane;
#pragma unroll
        for (int i = 0; i < HR; ++i) iv0[i] = __builtin_nontemporal_load(ip + i * 64);
    } else {
#pragma unroll
        for (int i = 0; i < HR; ++i) {
            int rr = tr0 + 2 * i + hi;
            if (rr >= NR) rr = NR - 1;
            iv0[i] = init[(size_t)rr * FF + f];
        }
    }

    // ---- P3: tile1 prep + descriptors (independent, overlaps t0 drain) ----
    float zm1;
    const int gidx1 = make_gidx(adj, mask, tr1, lane, NR, V, mask_index, zm1);
    int gp1[HR];
#pragma unroll
    for (int i = 0; i < HR; ++i)
        gp1[i] = __builtin_amdgcn_ds_bpermute((i << 3) + vhi4, gidx1);

    // ---- P4: tile0 LDS writes (progressive vmcnt on t0 loads) ----
    float* w0 = &sROW[w][0][0][0] + hi * STRIDE + f;
#pragma unroll
    for (int i = 0; i < HR; ++i)
        w0[i * (2 * STRIDE)] = ((gp0[i] & 1) ? 0.f : g0[i]) + iv0[i];

    // ---- P5: tile1 loads issued, NOT waited (drain under t0 compute) ----
    float g1[HR], iv1[HR];
#pragma unroll
    for (int i = 0; i < HR; ++i)
        g1[i] = *(const float*)(sum_bytes + (uint32_t)((gp1[i] & ~127) | (f << 2)));
    if (full1) {
        const float* ip = init + (size_t)tr1 * FF + lane;
#pragma unroll
        for (int i = 0; i < HR; ++i) iv1[i] = __builtin_nontemporal_load(ip + i * 64);
    } else {
#pragma unroll
        for (int i = 0; i < HR; ++i) {
            int rr = tr1 + 2 * i + hi;
            if (rr >= NR) rr = NR - 1;
            iv1[i] = init[(size_t)rr * FF + f];
        }
    }
    __builtin_amdgcn_sched_barrier(0);   // pin: t1 loads may not sink below

    // ---- stage-2 lane mapping ----
    int p_raw = lane / DD;
    int r_own = lane - p_raw * DD;
    const int pe   = (p_raw < PPW) ? p_raw : (PPW - 1);
    const int slot = pe * DD + r_own;
    const bool own = (p_raw < PPW);

    const f32x2* W2 = (const f32x2*)Wk;
    const f32x2* b2 = (const f32x2*)Wb;
    const f32x2* A2 = (const f32x2*)Ak;

    // ---- P6: tile0 compute + store (hides t1 memory latency) ----
    process_tile(&sROW[w][0][0][0], tr0, zm0, lane, slot, own, pe,
                 W2, b2, A2, out, NR);
    __builtin_amdgcn_sched_barrier(0);   // pin: t1 LDS writes stay below

    // ---- P7: tile1 LDS writes (loads drained during P6) ----
    float* w1 = &sROW[w][1][0][0] + hi * STRIDE + f;
#pragma unroll
    for (int i = 0; i < HR; ++i)
        w1[i * (2 * STRIDE)] = ((gp1[i] & 1) ? 0.f : g1[i]) + iv1[i];

    // ---- P8: tile1 compute + store ----
    process_tile(&sROW[w][1][0][0], tr1, zm1, lane, slot, own, pe,
                 W2, b2, A2, out, NR);
}

extern "C" void kernel_launch(void* const* d_in, const int* in_sizes, int n_in,
                              void* d_out, int out_size, void* d_ws, size_t ws_size,
                              hipStream_t stream) {
    const float* inputs = (const float*)d_in[0];
    const float* init   = (const float*)d_in[1];
    const float* mask   = (const float*)d_in[2];
    const float* Wk     = (const float*)d_in[3];
    const float* Wb     = (const float*)d_in[4];
    const float* Ak     = (const float*)d_in[5];
    const int*   adj    = (const int*)d_in[6];
    const int*   mip    = (const int*)d_in[7];

    const int B   = 4;
    const int BVD = in_sizes[2];          // B*V*D
    const int V   = BVD / (B * DD);
    const int BV  = B * V;

    float* summed = (float*)d_ws;         // B*V*FF floats = 10.24 MB
    int n4 = BV * (FF / 4);
    hipLaunchKernelGGL(sum_d4_kernel, dim3((n4 + 255) / 256), dim3(256), 0, stream,
                       (const f32x4*)inputs, (f32x4*)summed, n4);
    const int ppb = NW * NTILE * PPW;     // 24 pairs per block
    hipLaunchKernelGGL(gat_kernel, dim3((BV + ppb - 1) / ppb), dim3(NT), 0, stream,
                       summed, init, mask, Wk, Wb, Ak, adj, mip, (float*)d_out, B, V);
}

// Round 11
// 79.043 us; speedup vs baseline: 1.0580x; 1.0580x over previous
//
#include <hip/hip_runtime.h>
#include <cmath>

#define DD     10
#define FF     32
#define OUTN   32
#define PPW    6                 // pairs per wave-tile (60 rows)
#define NW     2                 // waves per block
#define NT     (NW * 64)
#define RPT    (PPW * DD)        // 60 rows per tile
#define NI     8                 // b128 staging instrs (8 rows each; last covers 4)
#define STRIDE 36                // LDS row stride in floats (144 B, 16B-aligned)

typedef float f32x4 __attribute__((ext_vector_type(4)));
typedef float f32x2 __attribute__((ext_vector_type(2)));

// Kernel 1: summed[b,v,f] = sum_d inputs[b,v,d,f]  — at its roofline
__global__ __launch_bounds__(256) void sum_d4_kernel(
    const f32x4* __restrict__ in, f32x4* __restrict__ out, int n4) {
    int idx = blockIdx.x * 256 + threadIdx.x;
    if (idx >= n4) return;
    int f4 = idx & 7;
    int bv = idx >> 3;
    const f32x4* p = in + (size_t)bv * (DD * 8) + f4;
    f32x4 s = __builtin_nontemporal_load(p);
#pragma unroll
    for (int d = 1; d < DD; ++d) s += __builtin_nontemporal_load(p + d * 8);
    out[idx] = s;
}

// Kernel 2: b128 staging (8 lanes/row) -> LDS transpose -> per-lane-row dense.
__global__ __launch_bounds__(NT) void gat_kernel(
    const float* __restrict__ summed,
    const float* __restrict__ init,
    const float* __restrict__ mask,
    const float* __restrict__ Wk,
    const float* __restrict__ Wb,
    const float* __restrict__ Ak,
    const int* __restrict__ adj,
    const int* __restrict__ mask_index_p,
    float* __restrict__ out,
    int B, int V) {
    __shared__ float sROW[NW][RPT][STRIDE];   // 17280 B -> 9 blocks/CU

    const int t    = threadIdx.x;
    const int lane = t & 63;
    const int w    = t >> 6;
    const int l8   = lane & 7;               // f32x4 chunk within row
    const int r8   = lane >> 3;              // row within 8-row group
    const int BV   = B * V;
    const int NR   = BV * DD;
    const int mask_index = *mask_index_p;

    const int wp0 = (blockIdx.x * NW + w) * PPW;
    const int tr0 = wp0 * DD;

    // ---- lane = slot prep: packed descriptor (row-offset | zmbit | maskbit) ----
    int sr = tr0 + lane;
    if (sr >= NR) sr = NR - 1;
    const int   a_s = adj[sr];
    const float m_s = mask[sr];
    int ac = a_s < 0 ? 0 : (a_s >= V ? V - 1 : a_s);        // JAX clamp
    int bv_s = sr / DD;
    int b_s  = (bv_s >= 2 * V) ? ((bv_s >= 3 * V) ? 3 : 2) : ((bv_s >= V) ? 1 : 0);
    const int gidx = ((b_s * V + ac) << 7) | ((m_s != 0.f) ? 2 : 0)
                   | ((a_s == mask_index) ? 1 : 0);

    // ---- init loads first (independent of adj chain), b128, clamped rows ----
    f32x4 iv[NI];
#pragma unroll
    for (int i = 0; i < NI; ++i) {
        int rr = tr0 + 8 * i + r8;
        if (rr >= NR) rr = NR - 1;
        iv[i] = __builtin_nontemporal_load((const f32x4*)(init + (size_t)rr * FF) + l8);
    }

    // ---- descriptors for my 8 staging instrs (src slot = 8i + r8) ----
    int gp[NI];
#pragma unroll
    for (int i = 0; i < NI; ++i)
        gp[i] = __builtin_amdgcn_ds_bpermute((8 * i + r8) << 2, gidx);

    // ---- gathers: 8 b128, each lane 16 B of its row ----
    const char* sb = (const char*)summed;
    f32x4 g[NI];
#pragma unroll
    for (int i = 0; i < NI; ++i)
        g[i] = *(const f32x4*)(sb + (uint32_t)(gp[i] & 0x7FFFFF80) + (l8 << 4));

    // ---- combine + LDS b128 writes (slot guard for the half-filled last instr) ----
    float* base = &sROW[w][0][0];
#pragma unroll
    for (int i = 0; i < NI; ++i) {
        int slot = 8 * i + r8;
        f32x4 v = iv[i];
        if (!(gp[i] & 1)) v += g[i];          // masked neighbor -> skip gather add
        if (slot < RPT)
            *(f32x4*)(base + slot * STRIDE + (l8 << 2)) = v;
    }
    // wave-local LDS: compiler-inserted lgkmcnt, no barrier needed

    // ---- stage 2: per-lane own row ----
    int p_raw = lane / DD;                    // 0..6
    int r_own = lane - p_raw * DD;
    const int pe   = (p_raw < PPW) ? p_raw : (PPW - 1);
    const int slot = pe * DD + r_own;         // <= 59
    const bool own = (p_raw < PPW);
    float* rowp = base + slot * STRIDE;

    f32x4 gi4[8];
#pragma unroll
    for (int q = 0; q < 8; ++q) gi4[q] = *(const f32x4*)(rowp + 4 * q);

    // zm of own row from the packed descriptor (one bpermute)
    const int fl_o = __builtin_amdgcn_ds_bpermute(slot << 2, gidx);
    const float zm_o = (fl_o & 2) ? 0.f : 1.f;

    // dense: dot = raw @ W (W/bias/a uniform -> s_load; f32x2 -> v_pk_fma_f32)
    const f32x2* W2 = (const f32x2*)Wk;
    const f32x2* b2 = (const f32x2*)Wb;
    const f32x2* A2 = (const f32x2*)Ak;
    f32x2 T2[16];
#pragma unroll
    for (int i = 0; i < 16; ++i) T2[i] = (f32x2){0.f, 0.f};
#pragma unroll
    for (int ff = 0; ff < FF; ++ff) {
        float gf = gi4[ff >> 2][ff & 3];
        f32x2 gf2 = {gf, gf};
#pragma unroll
        for (int i = 0; i < 16; ++i) T2[i] = gf2 * W2[ff * 16 + i] + T2[i];
    }
    // T = relu(zm*dot + bias) * zm ; attn dot in-lane
    f32x2 z2 = {zm_o, zm_o};
    f32x2 acc2 = {0.f, 0.f};
#pragma unroll
    for (int i = 0; i < 16; ++i) {
        f32x2 v = z2 * T2[i] + b2[i];
        v.x = fmaxf(v.x, 0.f);
        v.y = fmaxf(v.y, 0.f);
        v = v * z2;
        T2[i] = v;
        acc2 = v * A2[i] + acc2;
    }
    const float aw = acc2.x + acc2.y - 1e7f * (1.f - zm_o);

    // softmax over the pair's 10 rows via ds_bpermute
    const int pe40 = pe * 40;
    float vals[DD];
    float mx = -INFINITY;
#pragma unroll
    for (int d = 0; d < DD; ++d) {
        vals[d] = __int_as_float(
            __builtin_amdgcn_ds_bpermute(pe40 + 4 * d, __float_as_int(aw)));
        mx = fmaxf(mx, vals[d]);
    }
    float den = 0.f;
#pragma unroll
    for (int d = 0; d < DD; ++d) den += __expf(vals[d] - mx);
    const float coef = __expf(aw - mx) / den;

    // writeback coef*T to own LDS row (guard: shadows would duplicate slots)
    if (own) {
        f32x2 c2 = {coef, coef};
#pragma unroll
        for (int q = 0; q < 8; ++q) {
            f32x2 lo = T2[2 * q] * c2;
            f32x2 hv = T2[2 * q + 1] * c2;
            f32x4 vv;
            vv.x = lo.x; vv.y = lo.y; vv.z = hv.x; vv.w = hv.y;
            *(f32x4*)(rowp + 4 * q) = vv;
        }
    }

    // ---- epilogue: coalesced nt b128 stores ----
    int nrows = NR - tr0;
    if (nrows < 0) nrows = 0;
    if (nrows > RPT) nrows = RPT;
    const int lim4 = nrows * 8;
    f32x4* ob = (f32x4*)(out + (size_t)tr0 * FF);
#pragma unroll
    for (int k = 0; k < 8; ++k) {
        int m = lane + (k << 6);
        if (m < lim4) {
            const f32x4 v = *(const f32x4*)(base + (m >> 3) * STRIDE + ((m & 7) << 2));
            __builtin_nontemporal_store(v, ob + m);
        }
    }
}

extern "C" void kernel_launch(void* const* d_in, const int* in_sizes, int n_in,
                              void* d_out, int out_size, void* d_ws, size_t ws_size,
                              hipStream_t stream) {
    const float* inputs = (const float*)d_in[0];
    const float* init   = (const float*)d_in[1];
    const float* mask   = (const float*)d_in[2];
    const float* Wk     = (const float*)d_in[3];
    const float* Wb     = (const float*)d_in[4];
    const float* Ak     = (const float*)d_in[5];
    const int*   adj    = (const int*)d_in[6];
    const int*   mip    = (const int*)d_in[7];

    const int B   = 4;
    const int BVD = in_sizes[2];          // B*V*D
    const int V   = BVD / (B * DD);
    const int BV  = B * V;

    float* summed = (float*)d_ws;         // B*V*FF floats = 10.24 MB
    int n4 = BV * (FF / 4);
    hipLaunchKernelGGL(sum_d4_kernel, dim3((n4 + 255) / 256), dim3(256), 0, stream,
                       (const f32x4*)inputs, (f32x4*)summed, n4);
    const int ppb = NW * PPW;             // 12 pairs per block
    hipLaunchKernelGGL(gat_kernel, dim3((BV + ppb - 1) / ppb), dim3(NT), 0, stream,
                       summed, init, mask, Wk, Wb, Ak, adj, mip, (float*)d_out, B, V);
}